// Round 5
// baseline (207.585 us; speedup 1.0000x reference)
//
#include <hip/hip_runtime.h>
#include <stdint.h>

typedef unsigned short u16;
typedef __bf16 bf16x8 __attribute__((ext_vector_type(8)));
typedef float f32x4 __attribute__((ext_vector_type(4)));
typedef float f32x2 __attribute__((ext_vector_type(2)));

#define M_ROWS 16384
#define K_DIM  1568
#define H_DIM  128
#define NQ     384             // P cols: 0-127 q(scaled), 128-255 k, 256-383 v
#define MT     64              // batch rows per proj block
#define BK     32
#define NSTEP  49              // K_DIM / BK
#define NCH    8               // full chunks of 6 ksteps
#define CH_F   192             // floats per row per chunk (6 ksteps)
#define ASTR   200             // chunk LDS row stride in u16 (192 + 8 pad)
#define TSTR   40              // tail LDS row stride in u16
#define ABUF   (MT * ASTR)     // 12800 u16 per chunk buffer
#define PSTR   132             // fused-path P row stride in f32
#define KSTRIDE (NQ * BK)      // wt2 elements per kstep = 12288
#define SCALE  0.02525381361380526f   // 1/sqrt(1568)
#define LOG2E  1.4426950408889634f

#define WS_NEEDED ((size_t)M_ROWS * NQ * 4 + (size_t)NSTEP * KSTRIDE * 2)

__device__ __forceinline__ u16 f32_to_bf16_rne(float f) {
    uint32_t u = __float_as_uint(f);
    uint32_t r = (u + 0x7FFFu + ((u >> 16) & 1u)) >> 16;
    return (u16)r;
}

__device__ __forceinline__ uint32_t cvt_pk(float lo, float hi) {
    uint32_t d;
    asm("v_cvt_pk_bf16_f32 %0, %1, %2" : "=v"(d) : "v"(lo), "v"(hi));
    return d;
}

__device__ __forceinline__ f32x2 pk_mul(f32x2 a, f32x2 b) {
    f32x2 d; asm("v_pk_mul_f32 %0, %1, %2" : "=v"(d) : "v"(a), "v"(b)); return d;
}
__device__ __forceinline__ f32x2 pk_add(f32x2 a, f32x2 b) {
    f32x2 d; asm("v_pk_add_f32 %0, %1, %2" : "=v"(d) : "v"(a), "v"(b)); return d;
}
__device__ __forceinline__ f32x2 pk_fma(f32x2 a, f32x2 b, f32x2 c) {
    f32x2 d; asm("v_pk_fma_f32 %0, %1, %2, %3" : "=v"(d) : "v"(a), "v"(b), "v"(c)); return d;
}

__device__ __forceinline__ void cvt_wr8(u16* dst, f32x4 v) {
    uint2 t; t.x = cvt_pk(v.x, v.y); t.y = cvt_pk(v.z, v.w);
    *(uint2*)dst = t;
}

#define MFMA(a, b, c) __builtin_amdgcn_mfma_f32_16x16x32_bf16(a, b, c, 0, 0, 0)

// ---------------------------------------------------------------------------
// Kernel 1: weights -> fragment-ordered wt2[(kstep*384 + n)*32 + klo] (bf16)
// ---------------------------------------------------------------------------
__global__ __launch_bounds__(256) void wtrans_kernel(
    const float* __restrict__ wq, const float* __restrict__ wk,
    const float* __restrict__ wv, u16* __restrict__ wt2)
{
    __shared__ u16 tile[32][33];
    const float* w = (blockIdx.z == 0) ? wq : (blockIdx.z == 1) ? wk : wv;
    const int k0 = blockIdx.x * 32;
    const int nloc0 = blockIdx.y * 32;
    const int ng0 = blockIdx.z * 128 + nloc0;

    const int tn = threadIdx.x & 31;
    const int tk = threadIdx.x >> 5;
    #pragma unroll
    for (int p = 0; p < 4; p++) {
        int kk = tk + p * 8;
        tile[kk][tn] = f32_to_bf16_rne(w[(size_t)(k0 + kk) * H_DIM + nloc0 + tn]);
    }
    __syncthreads();

    const int klo = threadIdx.x & 31;
    const int tn2 = threadIdx.x >> 5;
    u16* dst = wt2 + (size_t)(k0 >> 5) * KSTRIDE;
    #pragma unroll
    for (int p = 0; p < 4; p++) {
        int nn = tn2 + p * 8;
        dst[(size_t)(ng0 + nn) * 32 + klo] = tile[klo][nn];
    }
}

// ===========================================================================
// Shared GEMM body (staging + MFMA loop). EPILOGUE is a macro hook.
// ===========================================================================
#define GEMM_BODY_DECLS \
    const int tid  = threadIdx.x; \
    const int lane = tid & 63; \
    const int wave = tid >> 6; \
    const int lrow = lane & 15; \
    const int quad = lane >> 4; \
    const int m0   = blockIdx.x * MT; \
    const u16* bp0 = wt2 + (size_t)(wave * 48 +  0 + lrow) * 32 + quad * 8; \
    const u16* bp1 = wt2 + (size_t)(wave * 48 + 16 + lrow) * 32 + quad * 8; \
    const u16* bp2 = wt2 + (size_t)(wave * 48 + 32 + lrow) * 32 + quad * 8; \
    const int srow = tid >> 3; \
    const int st8  = tid & 7; \
    const float* xrow = x + (size_t)(m0 + srow) * K_DIM; \
    u16* wbs[2]; \
    wbs[0] = A0 + srow * ASTR + st8 * 4; \
    wbs[1] = A1 + srow * ASTR + st8 * 4; \
    const u16* aF[2][4]; \
    _Pragma("unroll") \
    for (int m = 0; m < 4; m++) { \
        aF[0][m] = A0 + (m * 16 + lrow) * ASTR + quad * 8; \
        aF[1][m] = A1 + (m * 16 + lrow) * ASTR + quad * 8; \
    }

#define NTLD4(off) __builtin_nontemporal_load((const f32x4*)(xrow + (off)))
#define LOADC(S, OFF) do { \
    S[0] = NTLD4((OFF) + st8 * 4 +   0); \
    S[1] = NTLD4((OFF) + st8 * 4 +  32); \
    S[2] = NTLD4((OFF) + st8 * 4 +  64); \
    S[3] = NTLD4((OFF) + st8 * 4 +  96); \
    S[4] = NTLD4((OFF) + st8 * 4 + 128); \
    S[5] = NTLD4((OFF) + st8 * 4 + 160); \
} while (0)
#define WRITEC(WB, S) do { \
    cvt_wr8((WB) +   0, S[0]); cvt_wr8((WB) +  32, S[1]); \
    cvt_wr8((WB) +  64, S[2]); cvt_wr8((WB) +  96, S[3]); \
    cvt_wr8((WB) + 128, S[4]); cvt_wr8((WB) + 160, S[5]); \
} while (0)

#define KSTEP(AP, IT, G) do { \
    int gp = (G) + 2; if (gp > NSTEP - 1) gp = NSTEP - 1; \
    const size_t o = (size_t)gp * KSTRIDE; \
    bf16x8 Bc0 = *(const bf16x8*)(bp0 + o); \
    bf16x8 Bc1 = *(const bf16x8*)(bp1 + o); \
    bf16x8 Bc2 = *(const bf16x8*)(bp2 + o); \
    bf16x8 a0 = *(const bf16x8*)((AP)[0] + (IT) * BK); \
    bf16x8 a1 = *(const bf16x8*)((AP)[1] + (IT) * BK); \
    bf16x8 a2 = *(const bf16x8*)((AP)[2] + (IT) * BK); \
    bf16x8 a3 = *(const bf16x8*)((AP)[3] + (IT) * BK); \
    acc00 = MFMA(a0, Ba0, acc00); acc10 = MFMA(a1, Ba0, acc10); \
    acc20 = MFMA(a2, Ba0, acc20); acc30 = MFMA(a3, Ba0, acc30); \
    acc01 = MFMA(a0, Ba1, acc01); acc11 = MFMA(a1, Ba1, acc11); \
    acc21 = MFMA(a2, Ba1, acc21); acc31 = MFMA(a3, Ba1, acc31); \
    acc02 = MFMA(a0, Ba2, acc02); acc12 = MFMA(a1, Ba2, acc12); \
    acc22 = MFMA(a2, Ba2, acc22); acc32 = MFMA(a3, Ba2, acc32); \
    Ba0 = Bb0; Ba1 = Bb1; Ba2 = Bb2; Bb0 = Bc0; Bb1 = Bc1; Bb2 = Bc2; \
} while (0)

#define GEMM_MAIN \
    f32x4 acc00 = {}, acc01 = {}, acc02 = {}; \
    f32x4 acc10 = {}, acc11 = {}, acc12 = {}; \
    f32x4 acc20 = {}, acc21 = {}, acc22 = {}; \
    f32x4 acc30 = {}, acc31 = {}, acc32 = {}; \
    f32x4 sreg[2][6]; \
    LOADC(sreg[0], 0); \
    f32x4 tl = NTLD4(1536 + st8 * 4); \
    LOADC(sreg[1], CH_F); \
    WRITEC(wbs[0], sreg[0]); \
    cvt_wr8(TB + srow * TSTR + st8 * 4, tl); \
    bf16x8 Ba0 = *(const bf16x8*)(bp0); \
    bf16x8 Ba1 = *(const bf16x8*)(bp1); \
    bf16x8 Ba2 = *(const bf16x8*)(bp2); \
    bf16x8 Bb0 = *(const bf16x8*)(bp0 + KSTRIDE); \
    bf16x8 Bb1 = *(const bf16x8*)(bp1 + KSTRIDE); \
    bf16x8 Bb2 = *(const bf16x8*)(bp2 + KSTRIDE); \
    __syncthreads(); \
    _Pragma("unroll") \
    for (int c = 0; c < NCH; ++c) { \
        if (c < NCH - 1) WRITEC(wbs[(c + 1) & 1], sreg[(c + 1) & 1]); \
        if (c < NCH - 2) LOADC(sreg[c & 1], (c + 2) * CH_F); \
        _Pragma("unroll") \
        for (int it = 0; it < 6; ++it) KSTEP(aF[c & 1], it, c * 6 + it); \
        __syncthreads(); \
    } \
    { \
        bf16x8 a0 = *(const bf16x8*)(TB + (lrow +  0) * TSTR + quad * 8); \
        bf16x8 a1 = *(const bf16x8*)(TB + (lrow + 16) * TSTR + quad * 8); \
        bf16x8 a2 = *(const bf16x8*)(TB + (lrow + 32) * TSTR + quad * 8); \
        bf16x8 a3 = *(const bf16x8*)(TB + (lrow + 48) * TSTR + quad * 8); \
        acc00 = MFMA(a0, Ba0, acc00); acc10 = MFMA(a1, Ba0, acc10); \
        acc20 = MFMA(a2, Ba0, acc20); acc30 = MFMA(a3, Ba0, acc30); \
        acc01 = MFMA(a0, Ba1, acc01); acc11 = MFMA(a1, Ba1, acc11); \
        acc21 = MFMA(a2, Ba1, acc21); acc31 = MFMA(a3, Ba1, acc31); \
        acc02 = MFMA(a0, Ba2, acc02); acc12 = MFMA(a1, Ba2, acc12); \
        acc22 = MFMA(a2, Ba2, acc22); acc32 = MFMA(a3, Ba2, acc32); \
    }

// ---------------------------------------------------------------------------
// Kernel 2a: projection only (split path). 512 thr, 64 rows/block, grid 256.
// Epilogue scatters q*scale/k/v straight to global P[M][384] f32.
// ---------------------------------------------------------------------------
__global__ __launch_bounds__(512, 2) void proj_kernel(
    const float* __restrict__ x, const u16* __restrict__ wt2,
    float* __restrict__ P)
{
    __shared__ char smem[2 * ABUF * 2 + MT * TSTR * 2];   // 56320 B
    u16* A0 = (u16*)smem;
    u16* A1 = A0 + ABUF;
    u16* TB = A1 + ABUF;

    GEMM_BODY_DECLS
    GEMM_MAIN

#define SCATG(ACC, MTi, NTi) do { \
    const int n   = wave * 48 + (NTi) * 16 + lrow; \
    const float sc = (n < 128) ? (SCALE * LOG2E) : 1.0f; \
    const int mrow = m0 + (MTi) * 16 + quad * 4; \
    _Pragma("unroll") for (int rr = 0; rr < 4; rr++) \
        __builtin_nontemporal_store(ACC[rr] * sc, &P[(size_t)(mrow + rr) * NQ + n]); \
} while (0)

    SCATG(acc00, 0, 0); SCATG(acc01, 0, 1); SCATG(acc02, 0, 2);
    SCATG(acc10, 1, 0); SCATG(acc11, 1, 1); SCATG(acc12, 1, 2);
    SCATG(acc20, 2, 0); SCATG(acc21, 2, 1); SCATG(acc22, 2, 2);
    SCATG(acc30, 3, 0); SCATG(acc31, 3, 1); SCATG(acc32, 3, 2);
}

// ---------------------------------------------------------------------------
// Kernel 2b: fused fallback (R3-proven, 85 us). Used when ws too small.
// ---------------------------------------------------------------------------
__global__ __launch_bounds__(512, 2) void fused_kernel(
    const float* __restrict__ x, const u16* __restrict__ wt2,
    float* __restrict__ out)
{
    __shared__ char smem[3 * MT * PSTR * 4];   // 101376 B
    u16* A0 = (u16*)smem;
    u16* A1 = A0 + ABUF;
    u16* TB = A1 + ABUF;
    float (*Pq)[PSTR] = (float (*)[PSTR])smem;
    float (*Pk)[PSTR] = (float (*)[PSTR])(smem + MT * PSTR * 4);
    float (*Pv)[PSTR] = (float (*)[PSTR])(smem + 2 * MT * PSTR * 4);

    GEMM_BODY_DECLS
    GEMM_MAIN
    __syncthreads();

#define SCAT(ACC, MTi, NTi) do { \
    const int base = wave * 48 + (NTi) * 16; \
    const int sel  = base >> 7; \
    const int col  = (base & 127) + lrow; \
    const int mrow = (MTi) * 16 + quad * 4; \
    if (sel == 0)      { _Pragma("unroll") for (int rr = 0; rr < 4; rr++) Pq[mrow + rr][col] = ACC[rr] * (SCALE * LOG2E); } \
    else if (sel == 1) { _Pragma("unroll") for (int rr = 0; rr < 4; rr++) Pk[mrow + rr][col] = ACC[rr]; } \
    else               { _Pragma("unroll") for (int rr = 0; rr < 4; rr++) Pv[mrow + rr][col] = ACC[rr]; } \
} while (0)

    SCAT(acc00, 0, 0); SCAT(acc01, 0, 1); SCAT(acc02, 0, 2);
    SCAT(acc10, 1, 0); SCAT(acc11, 1, 1); SCAT(acc12, 1, 2);
    SCAT(acc20, 2, 0); SCAT(acc21, 2, 1); SCAT(acc22, 2, 2);
    SCAT(acc30, 3, 0); SCAT(acc31, 3, 1); SCAT(acc32, 3, 2);
    __syncthreads();

    const int r   = tid >> 3;
    const int sub = tid & 7;

    f32x4 qa = *(const f32x4*)&Pq[r][sub * 16 +  0];
    f32x4 qb = *(const f32x4*)&Pq[r][sub * 16 +  4];
    f32x4 qc = *(const f32x4*)&Pq[r][sub * 16 +  8];
    f32x4 qd = *(const f32x4*)&Pq[r][sub * 16 + 12];
    f32x2 qp0; qp0.x = qa.x; qp0.y = qa.y;
    f32x2 qp1; qp1.x = qa.z; qp1.y = qa.w;
    f32x2 qp2; qp2.x = qb.x; qp2.y = qb.y;
    f32x2 qp3; qp3.x = qb.z; qp3.y = qb.w;
    f32x2 qp4; qp4.x = qc.x; qp4.y = qc.y;
    f32x2 qp5; qp5.x = qc.z; qp5.y = qc.w;
    f32x2 qp6; qp6.x = qd.x; qp6.y = qd.y;
    f32x2 qp7; qp7.x = qd.z; qp7.y = qd.w;

    f32x2 d0 = {}, d1 = {}, d2 = {}, d3 = {}, d4 = {}, d5 = {}, d6 = {}, d7 = {};
    f32x2 n0 = {}, n1 = {}, n2 = {}, n3 = {}, n4 = {}, n5 = {}, n6 = {}, n7 = {};

    #pragma unroll 2
    for (int j4 = 0; j4 < 32; ++j4) {
        f32x4 k4 = *(const f32x4*)&Pk[r][j4 * 4];
        f32x4 v4 = *(const f32x4*)&Pv[r][j4 * 4];
        #pragma unroll
        for (int jj = 0; jj < 4; ++jj) {
            float kj = k4[jj];
            float vj = v4[jj];
            f32x2 kk; kk.x = kj; kk.y = kj;
            f32x2 vv; vv.x = vj; vv.y = vj;
            f32x2 s0 = pk_mul(qp0, kk);
            f32x2 s1 = pk_mul(qp1, kk);
            f32x2 s2 = pk_mul(qp2, kk);
            f32x2 s3 = pk_mul(qp3, kk);
            f32x2 s4 = pk_mul(qp4, kk);
            f32x2 s5 = pk_mul(qp5, kk);
            f32x2 s6 = pk_mul(qp6, kk);
            f32x2 s7 = pk_mul(qp7, kk);
            f32x2 e0; e0.x = __builtin_amdgcn_exp2f(s0.x); e0.y = __builtin_amdgcn_exp2f(s0.y);
            f32x2 e1; e1.x = __builtin_amdgcn_exp2f(s1.x); e1.y = __builtin_amdgcn_exp2f(s1.y);
            f32x2 e2; e2.x = __builtin_amdgcn_exp2f(s2.x); e2.y = __builtin_amdgcn_exp2f(s2.y);
            f32x2 e3; e3.x = __builtin_amdgcn_exp2f(s3.x); e3.y = __builtin_amdgcn_exp2f(s3.y);
            f32x2 e4; e4.x = __builtin_amdgcn_exp2f(s4.x); e4.y = __builtin_amdgcn_exp2f(s4.y);
            f32x2 e5; e5.x = __builtin_amdgcn_exp2f(s5.x); e5.y = __builtin_amdgcn_exp2f(s5.y);
            f32x2 e6; e6.x = __builtin_amdgcn_exp2f(s6.x); e6.y = __builtin_amdgcn_exp2f(s6.y);
            f32x2 e7; e7.x = __builtin_amdgcn_exp2f(s7.x); e7.y = __builtin_amdgcn_exp2f(s7.y);
            d0 = pk_add(d0, e0); n0 = pk_fma(e0, vv, n0);
            d1 = pk_add(d1, e1); n1 = pk_fma(e1, vv, n1);
            d2 = pk_add(d2, e2); n2 = pk_fma(e2, vv, n2);
            d3 = pk_add(d3, e3); n3 = pk_fma(e3, vv, n3);
            d4 = pk_add(d4, e4); n4 = pk_fma(e4, vv, n4);
            d5 = pk_add(d5, e5); n5 = pk_fma(e5, vv, n5);
            d6 = pk_add(d6, e6); n6 = pk_fma(e6, vv, n6);
            d7 = pk_add(d7, e7); n7 = pk_fma(e7, vv, n7);
        }
    }

    float* op = out + (size_t)(m0 + r) * H_DIM + sub * 16;
    f32x4 o0, o1, o2, o3;
    o0.x = n0.x / d0.x; o0.y = n0.y / d0.y; o0.z = n1.x / d1.x; o0.w = n1.y / d1.y;
    o1.x = n2.x / d2.x; o1.y = n2.y / d2.y; o1.z = n3.x / d3.x; o1.w = n3.y / d3.y;
    o2.x = n4.x / d4.x; o2.y = n4.y / d4.y; o2.z = n5.x / d5.x; o2.w = n5.y / d5.y;
    o3.x = n6.x / d6.x; o3.y = n6.y / d6.y; o3.z = n7.x / d7.x; o3.w = n7.y / d7.y;
    __builtin_nontemporal_store(o0, (f32x4*)(op +  0));
    __builtin_nontemporal_store(o1, (f32x4*)(op +  4));
    __builtin_nontemporal_store(o2, (f32x4*)(op +  8));
    __builtin_nontemporal_store(o3, (f32x4*)(op + 12));
}

// ---------------------------------------------------------------------------
// Kernel 3: rank-1 softmax attention (split path). 256 thr, 16 rows/block.
// Zero LDS -> max occupancy; trans (exp2) pipe is the floor.
// ---------------------------------------------------------------------------
__global__ __launch_bounds__(256) void attn_kernel(
    const float* __restrict__ P,     // [M,384] fp32
    float* __restrict__ out)         // [M,128] fp32
{
    const int tid  = threadIdx.x;
    const int rloc = tid >> 4;       // 0..15
    const int sub  = tid & 15;       // 16 threads/row, 8 outputs each
    const int row  = blockIdx.x * 16 + rloc;
    const float* pr = P + (size_t)row * NQ;

    f32x4 qa = *(const f32x4*)(pr + sub * 8);
    f32x4 qb = *(const f32x4*)(pr + sub * 8 + 4);
    f32x2 qp0; qp0.x = qa.x; qp0.y = qa.y;
    f32x2 qp1; qp1.x = qa.z; qp1.y = qa.w;
    f32x2 qp2; qp2.x = qb.x; qp2.y = qb.y;
    f32x2 qp3; qp3.x = qb.z; qp3.y = qb.w;

    f32x2 d0 = {}, d1 = {}, d2 = {}, d3 = {};
    f32x2 n0 = {}, n1 = {}, n2 = {}, n3 = {};

    #pragma unroll 4
    for (int j4 = 0; j4 < 32; ++j4) {
        f32x4 k4 = *(const f32x4*)(pr + 128 + j4 * 4);
        f32x4 v4 = *(const f32x4*)(pr + 256 + j4 * 4);
        #pragma unroll
        for (int jj = 0; jj < 4; ++jj) {
            float kj = k4[jj];
            float vj = v4[jj];
            f32x2 kk; kk.x = kj; kk.y = kj;
            f32x2 vv; vv.x = vj; vv.y = vj;
            f32x2 s0 = pk_mul(qp0, kk);
            f32x2 s1 = pk_mul(qp1, kk);
            f32x2 s2 = pk_mul(qp2, kk);
            f32x2 s3 = pk_mul(qp3, kk);
            f32x2 e0; e0.x = __builtin_amdgcn_exp2f(s0.x); e0.y = __builtin_amdgcn_exp2f(s0.y);
            f32x2 e1; e1.x = __builtin_amdgcn_exp2f(s1.x); e1.y = __builtin_amdgcn_exp2f(s1.y);
            f32x2 e2; e2.x = __builtin_amdgcn_exp2f(s2.x); e2.y = __builtin_amdgcn_exp2f(s2.y);
            f32x2 e3; e3.x = __builtin_amdgcn_exp2f(s3.x); e3.y = __builtin_amdgcn_exp2f(s3.y);
            d0 = pk_add(d0, e0); n0 = pk_fma(e0, vv, n0);
            d1 = pk_add(d1, e1); n1 = pk_fma(e1, vv, n1);
            d2 = pk_add(d2, e2); n2 = pk_fma(e2, vv, n2);
            d3 = pk_add(d3, e3); n3 = pk_fma(e3, vv, n3);
        }
    }

    float* op = out + (size_t)row * H_DIM + sub * 8;
    f32x4 o0, o1;
    o0.x = n0.x / d0.x; o0.y = n0.y / d0.y; o0.z = n1.x / d1.x; o0.w = n1.y / d1.y;
    o1.x = n2.x / d2.x; o1.y = n2.y / d2.y; o1.z = n3.x / d3.x; o1.w = n3.y / d3.y;
    __builtin_nontemporal_store(o0, (f32x4*)(op));
    __builtin_nontemporal_store(o1, (f32x4*)(op + 4));
}

// ---------------------------------------------------------------------------
extern "C" void kernel_launch(void* const* d_in, const int* in_sizes, int n_in,
                              void* d_out, int out_size, void* d_ws, size_t ws_size,
                              hipStream_t stream)
{
    const float* x  = (const float*)d_in[0];
    const float* wq = (const float*)d_in[1];
    const float* wk = (const float*)d_in[2];
    const float* wv = (const float*)d_in[3];
    float* out = (float*)d_out;

    if (ws_size >= WS_NEEDED) {
        // split path: P [25.17 MB] | wt2 [1.2 MB]
        float* P   = (float*)d_ws;
        u16*   wt2 = (u16*)((char*)d_ws + (size_t)M_ROWS * NQ * 4);
        wtrans_kernel<<<dim3(K_DIM / 32, H_DIM / 32, 3), 256, 0, stream>>>(wq, wk, wv, wt2);
        proj_kernel<<<M_ROWS / MT, 512, 0, stream>>>(x, wt2, P);
        attn_kernel<<<M_ROWS / 16, 256, 0, stream>>>(P, out);
    } else {
        // fused fallback (R3-proven): only wt2 [1.2 MB] needed
        u16* wt2 = (u16*)d_ws;
        wtrans_kernel<<<dim3(K_DIM / 32, H_DIM / 32, 3), 256, 0, stream>>>(wq, wk, wv, wt2);
        fused_kernel<<<M_ROWS / MT, 512, 0, stream>>>(x, wt2, out);
    }
}

// Round 6
// 205.235 us; speedup vs baseline: 1.0114x; 1.0114x over previous
//
#include <hip/hip_runtime.h>
#include <stdint.h>

typedef unsigned short u16;
typedef __bf16 bf16x8 __attribute__((ext_vector_type(8)));
typedef float f32x4 __attribute__((ext_vector_type(4)));
typedef float f32x2 __attribute__((ext_vector_type(2)));

#define M_ROWS 16384
#define K_DIM  1568
#define H_DIM  128
#define NQ     384
#define MT     32              // batch rows per block; grid 512 = 2 blocks/CU
#define BK     32
#define NSTEP  49              // K_DIM / BK
#define NCH    8               // full chunks of 6 ksteps
#define CHK    6               // ksteps per chunk
#define CH_F   192             // floats per row per chunk
#define ASTR   200             // chunk LDS row stride in u16 (192 + 8 pad)
#define TSTR   40              // tail LDS row stride in u16
#define ABUF   (MT * ASTR)     // 6400 u16 per chunk buffer
#define PSTR   132             // P row stride in f32
#define KSTRIDE (NQ * BK)      // wt2 elements per kstep = 12288
#define SCALE  0.02525381361380526f   // 1/sqrt(1568)
#define LOG2E  1.4426950408889634f

__device__ __forceinline__ u16 f32_to_bf16_rne(float f) {
    uint32_t u = __float_as_uint(f);
    uint32_t r = (u + 0x7FFFu + ((u >> 16) & 1u)) >> 16;
    return (u16)r;
}

__device__ __forceinline__ uint32_t cvt_pk(float lo, float hi) {
    uint32_t d;
    asm("v_cvt_pk_bf16_f32 %0, %1, %2" : "=v"(d) : "v"(lo), "v"(hi));
    return d;
}

__device__ __forceinline__ f32x2 pk_mul(f32x2 a, f32x2 b) {
    f32x2 d; asm("v_pk_mul_f32 %0, %1, %2" : "=v"(d) : "v"(a), "v"(b)); return d;
}
__device__ __forceinline__ f32x2 pk_add(f32x2 a, f32x2 b) {
    f32x2 d; asm("v_pk_add_f32 %0, %1, %2" : "=v"(d) : "v"(a), "v"(b)); return d;
}
__device__ __forceinline__ f32x2 pk_fma(f32x2 a, f32x2 b, f32x2 c) {
    f32x2 d; asm("v_pk_fma_f32 %0, %1, %2, %3" : "=v"(d) : "v"(a), "v"(b), "v"(c)); return d;
}

__device__ __forceinline__ void cvt_wr8(u16* dst, f32x4 v) {
    uint2 t; t.x = cvt_pk(v.x, v.y); t.y = cvt_pk(v.z, v.w);
    *(uint2*)dst = t;
}

#define MFMA(a, b, c) __builtin_amdgcn_mfma_f32_16x16x32_bf16(a, b, c, 0, 0, 0)

// ---------------------------------------------------------------------------
// Kernel 1: weights -> fragment-ordered wt2[(kstep*384 + n)*32 + klo] (bf16)
// ---------------------------------------------------------------------------
__global__ __launch_bounds__(256) void wtrans_kernel(
    const float* __restrict__ wq, const float* __restrict__ wk,
    const float* __restrict__ wv, u16* __restrict__ wt2)
{
    __shared__ u16 tile[32][33];
    const float* w = (blockIdx.z == 0) ? wq : (blockIdx.z == 1) ? wk : wv;
    const int k0 = blockIdx.x * 32;
    const int nloc0 = blockIdx.y * 32;
    const int ng0 = blockIdx.z * 128 + nloc0;

    const int tn = threadIdx.x & 31;
    const int tk = threadIdx.x >> 5;
    #pragma unroll
    for (int p = 0; p < 4; p++) {
        int kk = tk + p * 8;
        tile[kk][tn] = f32_to_bf16_rne(w[(size_t)(k0 + kk) * H_DIM + nloc0 + tn]);
    }
    __syncthreads();

    const int klo = threadIdx.x & 31;
    const int tn2 = threadIdx.x >> 5;
    u16* dst = wt2 + (size_t)(k0 >> 5) * KSTRIDE;
    #pragma unroll
    for (int p = 0; p < 4; p++) {
        int nn = tn2 + p * 8;
        dst[(size_t)(ng0 + nn) * 32 + klo] = tile[klo][nn];
    }
}

// ---------------------------------------------------------------------------
// Kernel 2 (fused): 512 threads = 8 waves, 32 rows/block, grid 512 -> 2
// blocks/CU (4 waves/SIMD). Light staging: 3 f32x4 regs/thread/chunk (6-kstep
// chunks, double-buffered LDS), depth-3 B register pipeline. Attention phase
// of one block overlaps GEMM of the co-resident block (trans vs MFMA pipes).
// ---------------------------------------------------------------------------
__global__ __launch_bounds__(512, 4) void fused_kernel(
    const float* __restrict__ x,     // [M,K] fp32
    const u16* __restrict__ wt2,     // fragment-ordered weights
    float* __restrict__ out)         // [M,H] fp32
{
    __shared__ char smem[3 * MT * PSTR * 4];   // 50688 B (P overlay is the max)
    u16* A0 = (u16*)smem;                       // 12800 B
    u16* A1 = A0 + ABUF;                        // 12800 B
    u16* TB = A1 + ABUF;                        // 2560 B
    float (*Pq)[PSTR] = (float (*)[PSTR])smem;
    float (*Pk)[PSTR] = (float (*)[PSTR])(smem + MT * PSTR * 4);
    float (*Pv)[PSTR] = (float (*)[PSTR])(smem + 2 * MT * PSTR * 4);

    const int tid  = threadIdx.x;
    const int lane = tid & 63;
    const int wave = tid >> 6;
    const int lrow = lane & 15;
    const int quad = lane >> 4;
    const int m0   = blockIdx.x * MT;

    // ---- B fragment pointers: contiguous 16B/lane in wt2 ----
    const u16* bp0 = wt2 + (size_t)(wave * 48 +  0 + lrow) * 32 + quad * 8;
    const u16* bp1 = wt2 + (size_t)(wave * 48 + 16 + lrow) * 32 + quad * 8;
    const u16* bp2 = wt2 + (size_t)(wave * 48 + 32 + lrow) * 32 + quad * 8;

    // ---- staging geometry: 16 threads/row, 12 f32 (3 x f32x4) each ----
    const int srow = tid >> 4;           // 0..31
    const int st16 = tid & 15;
    const float* xrow = x + (size_t)(m0 + srow) * K_DIM;
    u16* wbs[2];
    wbs[0] = A0 + srow * ASTR + st16 * 12;
    wbs[1] = A1 + srow * ASTR + st16 * 12;

    // ---- A fragment read pointers (2 m-frags per buffer) ----
    const u16* aF[2][2];
    #pragma unroll
    for (int m = 0; m < 2; m++) {
        aF[0][m] = A0 + (m * 16 + lrow) * ASTR + quad * 8;
        aF[1][m] = A1 + (m * 16 + lrow) * ASTR + quad * 8;
    }

#define LD4(off) (*(const f32x4*)(xrow + (off)))
#define LOADC(S, OFF) do { \
    S[0] = LD4((OFF) + st16 * 12 + 0); \
    S[1] = LD4((OFF) + st16 * 12 + 4); \
    S[2] = LD4((OFF) + st16 * 12 + 8); \
} while (0)
#define WRITEC(WB, S) do { \
    cvt_wr8((WB) + 0, S[0]); cvt_wr8((WB) + 4, S[1]); cvt_wr8((WB) + 8, S[2]); \
} while (0)

    f32x4 acc00 = {}, acc01 = {}, acc02 = {};
    f32x4 acc10 = {}, acc11 = {}, acc12 = {};
    f32x4 sreg[2][3];

    // ================= prologue: chunk0 staged, chunk1 in flight, tail =====
    LOADC(sreg[0], 0);
    f32x2 tl = *(const f32x2*)(xrow + 1536 + st16 * 2);
    LOADC(sreg[1], CH_F);
    WRITEC(wbs[0], sreg[0]);
    *(uint32_t*)(TB + srow * TSTR + st16 * 2) = cvt_pk(tl.x, tl.y);

    // ---- B depth-3 register pipeline prologue (ksteps 0,1,2 in flight) ----
    bf16x8 Ba0 = *(const bf16x8*)(bp0);
    bf16x8 Ba1 = *(const bf16x8*)(bp1);
    bf16x8 Ba2 = *(const bf16x8*)(bp2);
    bf16x8 Bb0 = *(const bf16x8*)(bp0 + KSTRIDE);
    bf16x8 Bb1 = *(const bf16x8*)(bp1 + KSTRIDE);
    bf16x8 Bb2 = *(const bf16x8*)(bp2 + KSTRIDE);
    bf16x8 Bc0 = *(const bf16x8*)(bp0 + 2 * KSTRIDE);
    bf16x8 Bc1 = *(const bf16x8*)(bp1 + 2 * KSTRIDE);
    bf16x8 Bc2 = *(const bf16x8*)(bp2 + 2 * KSTRIDE);
    __syncthreads();

#define KSTEP(AP, IT, G) do { \
    int gp = (G) + 3; if (gp > NSTEP - 1) gp = NSTEP - 1; \
    const size_t o = (size_t)gp * KSTRIDE; \
    bf16x8 Bd0 = *(const bf16x8*)(bp0 + o); \
    bf16x8 Bd1 = *(const bf16x8*)(bp1 + o); \
    bf16x8 Bd2 = *(const bf16x8*)(bp2 + o); \
    bf16x8 a0 = *(const bf16x8*)((AP)[0] + (IT) * BK); \
    bf16x8 a1 = *(const bf16x8*)((AP)[1] + (IT) * BK); \
    acc00 = MFMA(a0, Ba0, acc00); acc10 = MFMA(a1, Ba0, acc10); \
    acc01 = MFMA(a0, Ba1, acc01); acc11 = MFMA(a1, Ba1, acc11); \
    acc02 = MFMA(a0, Ba2, acc02); acc12 = MFMA(a1, Ba2, acc12); \
    Ba0 = Bb0; Ba1 = Bb1; Ba2 = Bb2; \
    Bb0 = Bc0; Bb1 = Bc1; Bb2 = Bc2; \
    Bc0 = Bd0; Bc1 = Bd1; Bc2 = Bd2; \
} while (0)

    // ===== 8 chunks: write c+1, issue c+2, compute c (fully unrolled) ======
    #pragma unroll
    for (int c = 0; c < NCH; ++c) {
        if (c < NCH - 1) WRITEC(wbs[(c + 1) & 1], sreg[(c + 1) & 1]);
        if (c < NCH - 2) LOADC(sreg[c & 1], (c + 2) * CH_F);
        #pragma unroll
        for (int it = 0; it < CHK; ++it) KSTEP(aF[c & 1], it, c * CHK + it);
        __syncthreads();
    }

    // ===== tail kstep 48 from TB (Ba holds g=48 fragments) ==================
    {
        bf16x8 a0 = *(const bf16x8*)(TB + (lrow +  0) * TSTR + quad * 8);
        bf16x8 a1 = *(const bf16x8*)(TB + (lrow + 16) * TSTR + quad * 8);
        acc00 = MFMA(a0, Ba0, acc00); acc10 = MFMA(a1, Ba0, acc10);
        acc01 = MFMA(a0, Ba1, acc01); acc11 = MFMA(a1, Ba1, acc11);
        acc02 = MFMA(a0, Ba2, acc02); acc12 = MFMA(a1, Ba2, acc12);
    }
    __syncthreads();   // all A/TB reads done before P overwrites the buffers

    // ---- scatter projections to LDS (D: row = quad*4+rr, col = lane&15) ---
#define SCAT(ACC, MTi, NTi) do { \
    const int base = wave * 48 + (NTi) * 16; \
    const int sel  = base >> 7; \
    const int col  = (base & 127) + lrow; \
    const int mrow = (MTi) * 16 + quad * 4; \
    if (sel == 0)      { _Pragma("unroll") for (int rr = 0; rr < 4; rr++) Pq[mrow + rr][col] = ACC[rr] * (SCALE * LOG2E); } \
    else if (sel == 1) { _Pragma("unroll") for (int rr = 0; rr < 4; rr++) Pk[mrow + rr][col] = ACC[rr]; } \
    else               { _Pragma("unroll") for (int rr = 0; rr < 4; rr++) Pv[mrow + rr][col] = ACC[rr]; } \
} while (0)

    SCAT(acc00, 0, 0); SCAT(acc01, 0, 1); SCAT(acc02, 0, 2);
    SCAT(acc10, 1, 0); SCAT(acc11, 1, 1); SCAT(acc12, 1, 2);
    __syncthreads();

    // ---- attention: r = row (32), sub (16) x 8 outputs each, packed f32 ---
    const int r   = tid >> 4;
    const int sub = tid & 15;

    f32x4 qa = *(const f32x4*)&Pq[r][sub * 8];
    f32x4 qb = *(const f32x4*)&Pq[r][sub * 8 + 4];
    f32x2 qp0; qp0.x = qa.x; qp0.y = qa.y;
    f32x2 qp1; qp1.x = qa.z; qp1.y = qa.w;
    f32x2 qp2; qp2.x = qb.x; qp2.y = qb.y;
    f32x2 qp3; qp3.x = qb.z; qp3.y = qb.w;

    f32x2 d0 = {}, d1 = {}, d2 = {}, d3 = {};
    f32x2 n0 = {}, n1 = {}, n2 = {}, n3 = {};

    #pragma unroll 4
    for (int j4 = 0; j4 < 32; ++j4) {
        f32x4 k4 = *(const f32x4*)&Pk[r][j4 * 4];
        f32x4 v4 = *(const f32x4*)&Pv[r][j4 * 4];
        #pragma unroll
        for (int jj = 0; jj < 4; ++jj) {
            float kj = k4[jj];
            float vj = v4[jj];
            f32x2 kk; kk.x = kj; kk.y = kj;
            f32x2 vv; vv.x = vj; vv.y = vj;
            f32x2 s0 = pk_mul(qp0, kk);
            f32x2 s1 = pk_mul(qp1, kk);
            f32x2 s2 = pk_mul(qp2, kk);
            f32x2 s3 = pk_mul(qp3, kk);
            f32x2 e0; e0.x = __builtin_amdgcn_exp2f(s0.x); e0.y = __builtin_amdgcn_exp2f(s0.y);
            f32x2 e1; e1.x = __builtin_amdgcn_exp2f(s1.x); e1.y = __builtin_amdgcn_exp2f(s1.y);
            f32x2 e2; e2.x = __builtin_amdgcn_exp2f(s2.x); e2.y = __builtin_amdgcn_exp2f(s2.y);
            f32x2 e3; e3.x = __builtin_amdgcn_exp2f(s3.x); e3.y = __builtin_amdgcn_exp2f(s3.y);
            d0 = pk_add(d0, e0); n0 = pk_fma(e0, vv, n0);
            d1 = pk_add(d1, e1); n1 = pk_fma(e1, vv, n1);
            d2 = pk_add(d2, e2); n2 = pk_fma(e2, vv, n2);
            d3 = pk_add(d3, e3); n3 = pk_fma(e3, vv, n3);
        }
    }

    float* op = out + (size_t)(m0 + r) * H_DIM + sub * 8;
    f32x4 o0, o1;
    o0.x = n0.x / d0.x; o0.y = n0.y / d0.y; o0.z = n1.x / d1.x; o0.w = n1.y / d1.y;
    o1.x = n2.x / d2.x; o1.y = n2.y / d2.y; o1.z = n3.x / d3.x; o1.w = n3.y / d3.y;
    __builtin_nontemporal_store(o0, (f32x4*)(op));
    __builtin_nontemporal_store(o1, (f32x4*)(op + 4));
}

// ---------------------------------------------------------------------------
extern "C" void kernel_launch(void* const* d_in, const int* in_sizes, int n_in,
                              void* d_out, int out_size, void* d_ws, size_t ws_size,
                              hipStream_t stream)
{
    const float* x  = (const float*)d_in[0];
    const float* wq = (const float*)d_in[1];
    const float* wk = (const float*)d_in[2];
    const float* wv = (const float*)d_in[3];
    float* out = (float*)d_out;

    u16* wt2 = (u16*)d_ws;   // 49*384*32 u16 = 1.2 MB

    wtrans_kernel<<<dim3(K_DIM / 32, H_DIM / 32, 3), 256, 0, stream>>>(wq, wk, wv, wt2);
    fused_kernel<<<M_ROWS / MT, 512, 0, stream>>>(x, wt2, out);
}